// Round 6
// baseline (215.321 us; speedup 1.0000x reference)
//
// =============================================================================
// Round 5 resubmission of the round-3/4 plan (previous two rounds failed on
// harness block-extraction, not kernel content).
//
// THEORY (from round-3 counters): the merged j-loop kernel spilled.
// VGPR_Count=80 while live state is ~124 floats (xs 30 + qs 30 + a 30 + l 10
// + chunks/addr) -> scratch spill traffic visible as WRITE_SIZE 30464->33720 KB
// and FETCH_SIZE 1212->1262 KB. Also ~5 per-lane v_cmp+exec-mask sequences per
// j iteration.
//
// FIXES:
//  1. __launch_bounds__(128, 2): register budget ~256 VGPRs (2 waves/SIMD
//     needed: 4 blocks/CU x 2 waves / 4 SIMDs; LDS 26KB x 4 = 106KB < 160KB).
//     Kills spills.
//  2. Octave-structured fully-unrolled j-loop: slot y owns rows t = 8m+y.
//     In octave o (j = 8o..8o+7): rows m>o unconditional (no cmp), row m==o
//     one cmp (jp<=y), rows m<o statically dead. Only row 4 (t=32+y, y<2)
//     keeps a per-j cmp; the y>=4 wave skips it via execz.
//
// PREDICTION: WRITE_SIZE 33720 -> ~30500 KB, FETCH_SIZE -> ~1212 KB (spills
// gone -- the verification signal), VGPR_Count 160-200, dur_us 65.4 -> 32-40,
// VALUBusy -> 70-80%, SQ_LDS_BANK_CONFLICT = 0, OccupancyPercent ~18.
// =============================================================================
#include <hip/hip_runtime.h>
#include <math.h>

#define N_LAYERS 4
#define SEQ      34
#define BATCH_N  16384
#define NE       16        // batch elements per block (lane & 15)
#define NSLOT    8         // query slots per element (lane >> 4)
#define NROW     5         // rows per slot: m=0..3 -> t=8m+y; m=4 -> t=32+y (y<2)
#define VOCAB    14
// (1/sqrt(3)) * log2(e): fold attention scale AND exp->exp2 into q
#define QSCALE   0.8329806647638704f

// attention inner body for row m at key position j (chunks c0,c1,c2 in scope)
// chunk0={k0,k1,k2,k3} chunk1={k4,k5,v0,v1} chunk2={v2,v3,v4,v5}
// head1: K=c0.xyz,       V=(c1.z,c1.w,c2.x) scaled by p1
// head2: K=(c0.w,c1.xy), V=(c2.y,c2.z,c2.w) scaled by p2
#define ATT_BODY(m)                                                        \
    {                                                                      \
        float s1 = qs[m][0]*c0.x + qs[m][1]*c0.y + qs[m][2]*c0.z;          \
        float s2 = qs[m][3]*c0.w + qs[m][4]*c1.x + qs[m][5]*c1.y;          \
        float p1 = __builtin_amdgcn_exp2f(s1);                             \
        float p2 = __builtin_amdgcn_exp2f(s2);                             \
        l1[m] += p1;          l2[m] += p2;                                 \
        a[m][0] += p1*c1.z;   a[m][1] += p1*c1.w;   a[m][2] += p1*c2.x;    \
        a[m][3] += p2*c2.y;   a[m][4] += p2*c2.z;   a[m][5] += p2*c2.w;    \
    }

__global__ __launch_bounds__(128, 2) void addtrans_kernel(
    const int*   __restrict__ idx,      // (B, 34)
    const float* __restrict__ tok_emb,  // (14, 3)
    const float* __restrict__ pos_enc,  // (34, 3)
    const float* __restrict__ ln_w,     // (4, 6)
    const float* __restrict__ ln_b,     // (4, 6)
    const float* __restrict__ q1w,      // (4, 3, 3)
    const float* __restrict__ k1w,
    const float* __restrict__ v1w,
    const float* __restrict__ q2w,
    const float* __restrict__ k2w,
    const float* __restrict__ v2w,
    const float* __restrict__ out_w,    // (4, 6, 6)
    const float* __restrict__ lnf_w,    // (6,)
    const float* __restrict__ lnf_b,    // (6,)
    const float* __restrict__ head_w,   // (14, 6)
    float* __restrict__ out)            // (B, 34, 14)
{
    // K/V for one layer, packed 3 float4 per (t, e), layout [chunk*SEQ+t][e]:
    // reads at fixed j are 16 consecutive float4, 4-way slot broadcast ->
    // conflict-free. +1 row pad (historical; harmless).
    __shared__ float4 kvs[3 * SEQ + 1][NE];

    const int x = threadIdx.x & (NE - 1);      // element
    const int y = threadIdx.x >> 4;            // slot 0..7
    const int b = (int)blockIdx.x * NE + x;

    // row table: m=0..3 always (t = 8m+y <= 31); m=4 only for y<2 (t=32,33)
    int tp[NROW];
    tp[0] = y;
    tp[1] = 8 + y;
    tp[2] = 16 + y;
    tp[3] = 24 + y;
    tp[4] = (y < 2) ? (32 + y) : -1;

    // ---- embedding ----
    float xs[NROW][6];
    #pragma unroll
    for (int k = 0; k < NROW; ++k) {
        const int t = tp[k];
        if (t >= 0) {
            const int tok = idx[(size_t)b * SEQ + t];
            xs[k][0] = tok_emb[tok * 3 + 0];
            xs[k][1] = tok_emb[tok * 3 + 1];
            xs[k][2] = tok_emb[tok * 3 + 2];
            xs[k][3] = pos_enc[t * 3 + 0];
            xs[k][4] = pos_enc[t * 3 + 1];
            xs[k][5] = pos_enc[t * 3 + 2];
        }
    }

    float qs[NROW][6];

    for (int l = 0; l < N_LAYERS; ++l) {
        __syncthreads();   // WAR: previous layer's attention reads complete

        // ---- phase 1: LN + q/k/v projections for each owned t, stage K/V ----
        #pragma unroll
        for (int k = 0; k < NROW; ++k) {
            const int t = tp[k];
            if (t >= 0) {
                float h[6];
                {
                    const float* v = xs[k];
                    float m = (v[0]+v[1]+v[2]+v[3]+v[4]+v[5]) * (1.0f/6.0f);
                    float var = 0.f;
                    #pragma unroll
                    for (int i = 0; i < 6; ++i) { float d = v[i]-m; var += d*d; }
                    var *= (1.0f/6.0f);
                    float r = rsqrtf(var + 1e-5f);
                    #pragma unroll
                    for (int i = 0; i < 6; ++i)
                        h[i] = (v[i]-m) * r * ln_w[l*6+i] + ln_b[l*6+i];
                }
                float kk[6], vv[6];
                #pragma unroll
                for (int i = 0; i < 3; ++i) {
                    const int w = l*9 + i*3;
                    qs[k][i]   = (q1w[w]*h[0] + q1w[w+1]*h[1] + q1w[w+2]*h[2]) * QSCALE;
                    kk[i]      =  k1w[w]*h[0] + k1w[w+1]*h[1] + k1w[w+2]*h[2];
                    vv[i]      =  v1w[w]*h[0] + v1w[w+1]*h[1] + v1w[w+2]*h[2];
                    qs[k][3+i] = (q2w[w]*h[3] + q2w[w+1]*h[4] + q2w[w+2]*h[5]) * QSCALE;
                    kk[3+i]    =  k2w[w]*h[3] + k2w[w+1]*h[4] + k2w[w+2]*h[5];
                    vv[3+i]    =  v2w[w]*h[3] + v2w[w+1]*h[4] + v2w[w+2]*h[5];
                }
                kvs[0*SEQ + t][x] = make_float4(kk[0], kk[1], kk[2], kk[3]);
                kvs[1*SEQ + t][x] = make_float4(kk[4], kk[5], vv[0], vv[1]);
                kvs[2*SEQ + t][x] = make_float4(vv[2], vv[3], vv[4], vv[5]);
            }
        }
        __syncthreads();   // RAW: K/V visible

        // ---- phase 2: octave-structured merged causal attention ----
        // single-pass softmax (no max subtract: |s*log2e| < 46, fp32-safe)
        float l1[NROW], l2[NROW], a[NROW][6];
        #pragma unroll
        for (int k = 0; k < NROW; ++k) {
            l1[k] = 0.f; l2[k] = 0.f;
            #pragma unroll
            for (int i = 0; i < 6; ++i) a[k][i] = 0.f;
        }

        #pragma unroll
        for (int o = 0; o < 4; ++o) {
            #pragma unroll
            for (int jp = 0; jp < 8; ++jp) {
                const int j = 8 * o + jp;
                float4 c0 = kvs[j][x];
                float4 c1 = kvs[SEQ + j][x];
                float4 c2 = kvs[2*SEQ + j][x];
                #pragma unroll
                for (int m = o + 1; m < 4; ++m) ATT_BODY(m);
                if (jp <= y)     ATT_BODY(o);
                if (j <= tp[4])  ATT_BODY(4);
            }
        }
        // tail j = 32, 33: only row 4 can be active
        #pragma unroll
        for (int j = 32; j < 34; ++j) {
            float4 c0 = kvs[j][x];
            float4 c1 = kvs[SEQ + j][x];
            float4 c2 = kvs[2*SEQ + j][x];
            if (j <= tp[4]) ATT_BODY(4);
        }

        // ---- epilogue: normalize, output projection + residual ----
        #pragma unroll
        for (int k = 0; k < NROW; ++k) {
            if (tp[k] >= 0) {
                const float i1 = __builtin_amdgcn_rcpf(l1[k]);
                const float i2 = __builtin_amdgcn_rcpf(l2[k]);
                float o6[6] = { a[k][0]*i1, a[k][1]*i1, a[k][2]*i1,
                                a[k][3]*i2, a[k][4]*i2, a[k][5]*i2 };
                #pragma unroll
                for (int i = 0; i < 6; ++i) {
                    const int w = l*36 + i*6;
                    xs[k][i] += out_w[w+0]*o6[0] + out_w[w+1]*o6[1] + out_w[w+2]*o6[2]
                              + out_w[w+3]*o6[3] + out_w[w+4]*o6[4] + out_w[w+5]*o6[5];
                }
            }
        }
    }

    // ---- final layernorm + head ----
    #pragma unroll
    for (int k = 0; k < NROW; ++k) {
        const int t = tp[k];
        if (t >= 0) {
            float hf[6];
            {
                const float* v = xs[k];
                float m = (v[0]+v[1]+v[2]+v[3]+v[4]+v[5]) * (1.0f/6.0f);
                float var = 0.f;
                #pragma unroll
                for (int i = 0; i < 6; ++i) { float d = v[i]-m; var += d*d; }
                var *= (1.0f/6.0f);
                float r = rsqrtf(var + 1e-5f);
                #pragma unroll
                for (int i = 0; i < 6; ++i)
                    hf[i] = (v[i]-m) * r * lnf_w[i] + lnf_b[i];
            }
            float lg[VOCAB];
            #pragma unroll
            for (int c = 0; c < VOCAB; ++c) {
                const int w = c*6;
                lg[c] = head_w[w+0]*hf[0] + head_w[w+1]*hf[1] + head_w[w+2]*hf[2]
                      + head_w[w+3]*hf[3] + head_w[w+4]*hf[4] + head_w[w+5]*hf[5];
            }
            float2* op = (float2*)(out + ((size_t)b * SEQ + t) * VOCAB);
            #pragma unroll
            for (int c = 0; c < 7; ++c)
                op[c] = make_float2(lg[2*c], lg[2*c+1]);
        }
    }
}

extern "C" void kernel_launch(void* const* d_in, const int* in_sizes, int n_in,
                              void* d_out, int out_size, void* d_ws, size_t ws_size,
                              hipStream_t stream) {
    const int*   idx     = (const int*)  d_in[0];
    const float* tok_emb = (const float*)d_in[1];
    const float* pos_enc = (const float*)d_in[2];
    const float* ln_w    = (const float*)d_in[3];
    const float* ln_b    = (const float*)d_in[4];
    const float* q1w     = (const float*)d_in[5];
    const float* k1w     = (const float*)d_in[6];
    const float* v1w     = (const float*)d_in[7];
    const float* q2w     = (const float*)d_in[8];
    const float* k2w     = (const float*)d_in[9];
    const float* v2w     = (const float*)d_in[10];
    const float* out_w   = (const float*)d_in[11];
    const float* lnf_w   = (const float*)d_in[12];
    const float* lnf_b   = (const float*)d_in[13];
    const float* head_w  = (const float*)d_in[14];
    float* out = (float*)d_out;

    const int grid = BATCH_N / NE;   // 1024 blocks of 128 threads
    addtrans_kernel<<<grid, NE * NSLOT, 0, stream>>>(
        idx, tok_emb, pos_enc, ln_w, ln_b,
        q1w, k1w, v1w, q2w, k2w, v2w,
        out_w, lnf_w, lnf_b, head_w, out);
}

// Round 7
// 148.319 us; speedup vs baseline: 1.4517x; 1.4517x over previous
//
// =============================================================================
// Round 7: segmented per-lane-j attention loop, single-wave blocks.
//
// POST-MORTEM R6: octave full-unroll spilled ~1KB/thread to scratch
// (WRITE_SIZE 169 MB, VALUBusy 25%). Fix: keep loops ROLLED; fix masking
// structurally.
//
// STRUCTURE: block = 64 threads = 1 wave. x = lane&7 (batch element),
// y = lane>>3 (slot 0..7). Slot y owns rows t = 8m+y (m=0..3), plus
// t = 32+y for y<2. Attention runs as a SEQUENCE of loops; j is a per-lane
// (vector) variable so each lane walks its own causal window:
//   seg0: j<=y     -> bodies {0,1,2,3,(4)}
//   seg1: j<=8+y   -> bodies {1,2,3,(4)}    (trip = 8 for EVERY lane)
//   seg2: j<=16+y  -> bodies {2,3,(4)}
//   seg3: j<=24+y  -> bodies {3,(4)}
//   seg4: j<=tp4   -> body  {4}             (only y<2 lanes iterate)
// Rows 0..3 incur ZERO wasted body issues in segs 1-3; row 4 runs at 25%
// lane util (16/64 lanes) -- accepted cost. LDS reads with lane-varying j
// are contiguous gathers (rows j0+y, cols x -> consecutive 16B) =
// conflict-free. Single-wave block => __syncthreads is ~free, no wave
// imbalance at barriers.
//
// PREDICTION: WRITE_SIZE -> ~30.5 MB, FETCH -> ~1.2 MB (no spill),
// dur 65.4 -> 26-34 us, VALUBusy 70-85%, VGPR 140-200, LDS ~13 KB.
// =============================================================================
#include <hip/hip_runtime.h>
#include <math.h>

#define N_LAYERS 4
#define SEQ      34
#define BATCH_N  16384
#define NE       8         // batch elements per block (lane & 7)
#define NROW     5         // rows per slot: m=0..3 -> t=8m+y; m=4 -> t=32+y (y<2)
#define VOCAB    14
// (1/sqrt(3)) * log2(e): fold attention scale AND exp->exp2 into q
#define QSCALE   0.8329806647638704f

// attention inner body for row m at per-lane key position j
// chunk0={k0,k1,k2,k3} chunk1={k4,k5,v0,v1} chunk2={v2,v3,v4,v5}
// head1: K=c0.xyz,       V=(c1.z,c1.w,c2.x) scaled by p1
// head2: K=(c0.w,c1.xy), V=(c2.y,c2.z,c2.w) scaled by p2
#define ATT_BODY(m)                                                        \
    {                                                                      \
        float s1 = qs[m][0]*c0.x + qs[m][1]*c0.y + qs[m][2]*c0.z;          \
        float s2 = qs[m][3]*c0.w + qs[m][4]*c1.x + qs[m][5]*c1.y;          \
        float p1 = __builtin_amdgcn_exp2f(s1);                             \
        float p2 = __builtin_amdgcn_exp2f(s2);                             \
        l1[m] += p1;          l2[m] += p2;                                 \
        a[m][0] += p1*c1.z;   a[m][1] += p1*c1.w;   a[m][2] += p1*c2.x;    \
        a[m][3] += p2*c2.y;   a[m][4] += p2*c2.z;   a[m][5] += p2*c2.w;    \
    }

#define LOAD_CHUNKS                                                        \
    float4 c0 = kvs[j][x];                                                 \
    float4 c1 = kvs[SEQ + j][x];                                           \
    float4 c2 = kvs[2*SEQ + j][x];

__global__ __launch_bounds__(64, 2) void addtrans_kernel(
    const int*   __restrict__ idx,      // (B, 34)
    const float* __restrict__ tok_emb,  // (14, 3)
    const float* __restrict__ pos_enc,  // (34, 3)
    const float* __restrict__ ln_w,     // (4, 6)
    const float* __restrict__ ln_b,     // (4, 6)
    const float* __restrict__ q1w,      // (4, 3, 3)
    const float* __restrict__ k1w,
    const float* __restrict__ v1w,
    const float* __restrict__ q2w,
    const float* __restrict__ k2w,
    const float* __restrict__ v2w,
    const float* __restrict__ out_w,    // (4, 6, 6)
    const float* __restrict__ lnf_w,    // (6,)
    const float* __restrict__ lnf_b,    // (6,)
    const float* __restrict__ head_w,   // (14, 6)
    float* __restrict__ out)            // (B, 34, 14)
{
    // K/V for one layer, packed 3 float4 per (t, e), layout [chunk*SEQ+t][e].
    // 13 KB/block -> 8 blocks/CU fits easily in 160 KB.
    __shared__ float4 kvs[3 * SEQ][NE];

    const int x = threadIdx.x & (NE - 1);      // element
    const int y = threadIdx.x >> 3;            // slot 0..7
    const int b = (int)blockIdx.x * NE + x;

    // row table: m=0..3 always (t = 8m+y <= 31); m=4 only for y<2 (t=32,33)
    int tp[NROW];
    tp[0] = y;
    tp[1] = 8 + y;
    tp[2] = 16 + y;
    tp[3] = 24 + y;
    tp[4] = (y < 2) ? (32 + y) : -1;
    const bool has4 = (y < 2);

    // ---- embedding ----
    float xs[NROW][6];
    #pragma unroll
    for (int k = 0; k < NROW; ++k) {
        const int t = tp[k];
        if (t >= 0) {
            const int tok = idx[(size_t)b * SEQ + t];
            xs[k][0] = tok_emb[tok * 3 + 0];
            xs[k][1] = tok_emb[tok * 3 + 1];
            xs[k][2] = tok_emb[tok * 3 + 2];
            xs[k][3] = pos_enc[t * 3 + 0];
            xs[k][4] = pos_enc[t * 3 + 1];
            xs[k][5] = pos_enc[t * 3 + 2];
        }
    }

    float qs[NROW][6];

    for (int l = 0; l < N_LAYERS; ++l) {
        __syncthreads();   // WAR (1-wave block: nearly free)

        // ---- phase 1: LN + q/k/v projections for each owned t, stage K/V ----
        #pragma unroll
        for (int k = 0; k < NROW; ++k) {
            const int t = tp[k];
            if (t >= 0) {
                float h[6];
                {
                    const float* v = xs[k];
                    float m = (v[0]+v[1]+v[2]+v[3]+v[4]+v[5]) * (1.0f/6.0f);
                    float var = 0.f;
                    #pragma unroll
                    for (int i = 0; i < 6; ++i) { float d = v[i]-m; var += d*d; }
                    var *= (1.0f/6.0f);
                    float r = rsqrtf(var + 1e-5f);
                    #pragma unroll
                    for (int i = 0; i < 6; ++i)
                        h[i] = (v[i]-m) * r * ln_w[l*6+i] + ln_b[l*6+i];
                }
                float kk[6], vv[6];
                #pragma unroll
                for (int i = 0; i < 3; ++i) {
                    const int w = l*9 + i*3;
                    qs[k][i]   = (q1w[w]*h[0] + q1w[w+1]*h[1] + q1w[w+2]*h[2]) * QSCALE;
                    kk[i]      =  k1w[w]*h[0] + k1w[w+1]*h[1] + k1w[w+2]*h[2];
                    vv[i]      =  v1w[w]*h[0] + v1w[w+1]*h[1] + v1w[w+2]*h[2];
                    qs[k][3+i] = (q2w[w]*h[3] + q2w[w+1]*h[4] + q2w[w+2]*h[5]) * QSCALE;
                    kk[3+i]    =  k2w[w]*h[3] + k2w[w+1]*h[4] + k2w[w+2]*h[5];
                    vv[3+i]    =  v2w[w]*h[3] + v2w[w+1]*h[4] + v2w[w+2]*h[5];
                }
                kvs[0*SEQ + t][x] = make_float4(kk[0], kk[1], kk[2], kk[3]);
                kvs[1*SEQ + t][x] = make_float4(kk[4], kk[5], vv[0], vv[1]);
                kvs[2*SEQ + t][x] = make_float4(vv[2], vv[3], vv[4], vv[5]);
            }
        }
        __syncthreads();   // RAW: K/V visible

        // ---- phase 2: segmented per-lane-j causal attention ----
        // single-pass softmax (no max subtract: |s*log2e| < 46, fp32-safe)
        float l1[NROW], l2[NROW], a[NROW][6];
        #pragma unroll
        for (int k = 0; k < NROW; ++k) {
            l1[k] = 0.f; l2[k] = 0.f;
            #pragma unroll
            for (int i = 0; i < 6; ++i) a[k][i] = 0.f;
        }

        int j = 0;                       // per-lane key position
        for (; j <= tp[0]; ++j) {        // seg0: all rows
            LOAD_CHUNKS
            ATT_BODY(0) ATT_BODY(1) ATT_BODY(2) ATT_BODY(3)
            if (has4) ATT_BODY(4)
        }
        for (; j <= tp[1]; ++j) {        // seg1: rows 1..3 (+4)
            LOAD_CHUNKS
            ATT_BODY(1) ATT_BODY(2) ATT_BODY(3)
            if (has4) ATT_BODY(4)
        }
        for (; j <= tp[2]; ++j) {        // seg2: rows 2..3 (+4)
            LOAD_CHUNKS
            ATT_BODY(2) ATT_BODY(3)
            if (has4) ATT_BODY(4)
        }
        for (; j <= tp[3]; ++j) {        // seg3: row 3 (+4)
            LOAD_CHUNKS
            ATT_BODY(3)
            if (has4) ATT_BODY(4)
        }
        for (; j <= tp[4]; ++j) {        // seg4: row 4 only (y<2 lanes)
            LOAD_CHUNKS
            ATT_BODY(4)
        }

        // ---- epilogue: normalize, output projection + residual ----
        #pragma unroll
        for (int k = 0; k < NROW; ++k) {
            if (tp[k] >= 0) {
                const float i1 = __builtin_amdgcn_rcpf(l1[k]);
                const float i2 = __builtin_amdgcn_rcpf(l2[k]);
                float o6[6] = { a[k][0]*i1, a[k][1]*i1, a[k][2]*i1,
                                a[k][3]*i2, a[k][4]*i2, a[k][5]*i2 };
                #pragma unroll
                for (int i = 0; i < 6; ++i) {
                    const int w = l*36 + i*6;
                    xs[k][i] += out_w[w+0]*o6[0] + out_w[w+1]*o6[1] + out_w[w+2]*o6[2]
                              + out_w[w+3]*o6[3] + out_w[w+4]*o6[4] + out_w[w+5]*o6[5];
                }
            }
        }
    }

    // ---- final layernorm + head ----
    #pragma unroll
    for (int k = 0; k < NROW; ++k) {
        const int t = tp[k];
        if (t >= 0) {
            float hf[6];
            {
                const float* v = xs[k];
                float m = (v[0]+v[1]+v[2]+v[3]+v[4]+v[5]) * (1.0f/6.0f);
                float var = 0.f;
                #pragma unroll
                for (int i = 0; i < 6; ++i) { float d = v[i]-m; var += d*d; }
                var *= (1.0f/6.0f);
                float r = rsqrtf(var + 1e-5f);
                #pragma unroll
                for (int i = 0; i < 6; ++i)
                    hf[i] = (v[i]-m) * r * lnf_w[i] + lnf_b[i];
            }
            float lg[VOCAB];
            #pragma unroll
            for (int c = 0; c < VOCAB; ++c) {
                const int w = c*6;
                lg[c] = head_w[w+0]*hf[0] + head_w[w+1]*hf[1] + head_w[w+2]*hf[2]
                      + head_w[w+3]*hf[3] + head_w[w+4]*hf[4] + head_w[w+5]*hf[5];
            }
            float2* op = (float2*)(out + ((size_t)b * SEQ + t) * VOCAB);
            #pragma unroll
            for (int c = 0; c < 7; ++c)
                op[c] = make_float2(lg[2*c], lg[2*c+1]);
        }
    }
}

extern "C" void kernel_launch(void* const* d_in, const int* in_sizes, int n_in,
                              void* d_out, int out_size, void* d_ws, size_t ws_size,
                              hipStream_t stream) {
    const int*   idx     = (const int*)  d_in[0];
    const float* tok_emb = (const float*)d_in[1];
    const float* pos_enc = (const float*)d_in[2];
    const float* ln_w    = (const float*)d_in[3];
    const float* ln_b    = (const float*)d_in[4];
    const float* q1w     = (const float*)d_in[5];
    const float* k1w     = (const float*)d_in[6];
    const float* v1w     = (const float*)d_in[7];
    const float* q2w     = (const float*)d_in[8];
    const float* k2w     = (const float*)d_in[9];
    const float* v2w     = (const float*)d_in[10];
    const float* out_w   = (const float*)d_in[11];
    const float* lnf_w   = (const float*)d_in[12];
    const float* lnf_b   = (const float*)d_in[13];
    const float* head_w  = (const float*)d_in[14];
    float* out = (float*)d_out;

    const int grid = BATCH_N / NE;   // 2048 blocks of 64 threads (1 wave each)
    addtrans_kernel<<<grid, 64, 0, stream>>>(
        idx, tok_emb, pos_enc, ln_w, ln_b,
        q1w, k1w, v1w, q2w, k2w, v2w,
        out_w, lnf_w, lnf_b, head_w, out);
}